// Round 8
// baseline (177.194 us; speedup 1.0000x reference)
//
#include <hip/hip_runtime.h>
#include <math.h>

// Problem constants
#define TT 8
#define BB 128
#define GG 256
#define DD 64
#define NCH 4     // D chunks (16 floats): one 64B line/thread/array/chunk,
                  // consumed in-phase (R5: smaller chunks -> L1 thrash, 2.7x slower)
#define CF4 4     // float4s per cell per chunk
#define ST 5      // LDS stride in float4s (20 dwords, period-8 full bank coverage;
                  // ST=4 was 8-way conflict: 1.02e7 SQ_LDS_BANK_CONFLICT, R4)
#define NPAIR ((TT - 1) * BB)
#define NBLK (NPAIR * 2)          // 2 half-grid blocks per pair
#define LROWS 10                  // 8 owned rows + 2 halo rows staged in LDS

// ws layout: part[blk*8 + j], j: 0 zdiff, 1 pres, 2 poolc(neg), 3 obj,
//                                4 flow_sq, 5 sum(zp), 6 sum(flow)

__device__ inline float wred(float v) {
#pragma unroll
    for (int off = 32; off > 0; off >>= 1) v += __shfl_xor(v, off, 64);
    return v;
}
__device__ inline float dot4(float4 a, float4 b) {
    return a.x * b.x + a.y * b.y + a.z * b.z + a.w * b.w;
}
__device__ inline float4 fabs4(float4 a) {
    return make_float4(fabsf(a.x), fabsf(a.y), fabsf(a.z), fabsf(a.w));
}
__device__ inline float4 max4(float4 a, float4 b) {
    return make_float4(fmaxf(a.x, b.x), fmaxf(a.y, b.y), fmaxf(a.z, b.z), fmaxf(a.w, b.w));
}
__device__ inline float4 scale4(float4 a, float s) {
    return make_float4(a.x * s, a.y * s, a.z * s, a.w * s);
}
__device__ inline float4 sub4(float4 a, float4 b) {
    return make_float4(a.x - b.x, a.y - b.y, a.z - b.z, a.w - b.w);
}
__device__ inline float4 shfl4(float4 v, int src) {
    return make_float4(__shfl(v.x, src, 64), __shfl(v.y, src, 64),
                       __shfl(v.z, src, 64), __shfl(v.w, src, 64));
}

// NOTE: no min-waves arg (R4: __launch_bounds__(256,4) -> VGPR=64 + 293 MB spill)
__global__ __launch_bounds__(128) void pair_kernel(const float* __restrict__ zw,
                                                   const float* __restrict__ zp,
                                                   const float* __restrict__ flow,
                                                   float* __restrict__ part) {
    const int blk = blockIdx.x;               // 0 .. NBLK-1
    const int pairIdx = blk >> 1;
    const int half = blk & 1;
    const int t = pairIdx >> 7;               // BB = 128
    const int b = pairIdx & (BB - 1);
    const int r0 = half << 3;                 // first owned global row (0 or 8)
    const int tid = threadIdx.x;              // 0..127 (2 waves)
    const int gj = tid & 15;                  // column
    const int grow = r0 + (tid >> 4);         // owned global row
    const int lr = (tid >> 4) + 1;            // owned local row 1..8
    const int cell = (grow << 4) | gj;
    const int lane = tid & 63;

    // halo duty: threads 0..31 also stage local rows 0 and 9 (wrapped rows)
    const bool isHalo = (tid < 32);
    const int hs = (tid < 16) ? 0 : 9;                  // local halo row
    const int hrow = (r0 - 1 + hs) & 15;                // wrapped global row
    const int hcell = (hrow << 4) | gj;

    __shared__ float4 shS[LROWS * 16 * ST];   // staging: B chunk, then row-max
    __shared__ float pAloc[LROWS * 16], pBloc[LROWS * 16], nBloc[LROWS * 16];
    __shared__ float bred[7][2];

    const float4* gA = (const float4*)zw + (size_t)(t * BB + b) * 1024;
    const float4* gB = gA + (size_t)BB * 1024;
    const float* zpA = zp + (size_t)(t * BB + b) * GG;
    const float* zpB = zp + (size_t)((t + 1) * BB + b) * GG;

    // ---- small loads + LDS p staging ----
    const float pAc = zpA[cell];
    const float pBc = zpB[cell];
    pAloc[lr * 16 + gj] = pAc;
    pBloc[lr * 16 + gj] = pBc;
    float pAh = 0.f;
    if (isHalo) {
        pAh = zpA[hcell];
        pAloc[hs * 16 + gj] = pAh;
        pBloc[hs * 16 + gj] = zpB[hcell];
    }
    const float f = flow[(size_t)(t * BB + b) * GG + cell];
    float f7 = 0.f, pC = 0.f;
    if (t == 6) f7 = flow[(size_t)(7 * BB + b) * GG + cell];
    if (t <= 5) pC = zp[(size_t)((t + 2) * BB + b) * GG + cell];

    // 9 neighbors in LOCAL rows (wrap handled by halo staging) + global in-bounds
    // mask (clamped ops: pool colmax / flow maxpool)
    int nbl[9];
    unsigned inbM = 0;
    {
        int m = 0;
#pragma unroll
        for (int di = -1; di <= 1; di++) {
#pragma unroll
            for (int dj = -1; dj <= 1; dj++) {
                nbl[m] = (lr + di) * 16 + ((gj + dj) & 15);
                if (((unsigned)(grow + di) < 16u) && ((unsigned)(gj + dj) < 16u))
                    inbM |= (1u << m);
                m++;
            }
        }
    }
    __syncthreads();

    float zdiff = 0.f, sa = 0.f, sb = 0.f, hsb = 0.f, poolDot = 0.f, poolN = 0.f;
    float dots[9] = {0.f, 0.f, 0.f, 0.f, 0.f, 0.f, 0.f, 0.f, 0.f};

    // unroll 1: full unroll hoists all chunks' loads and spills (R2 post-mortem)
#pragma unroll 1
    for (int c = 0; c < NCH; c++) {
        float4 cA[CF4], cB[CF4], rm[CF4], hrm[CF4];
#pragma unroll
        for (int q = 0; q < CF4; q++) {
            cA[q] = gA[cell * 16 + c * CF4 + q];
            cB[q] = gB[cell * 16 + c * CF4 + q];
        }
        float4 hB4[CF4];
        if (isHalo) {
            // halo loads (wrapped row); also compute halo row-max of wa and sb
#pragma unroll
            for (int q = 0; q < CF4; q++) {
                float4 hA4 = gA[hcell * 16 + c * CF4 + q];
                hB4[q] = gB[hcell * 16 + c * CF4 + q];
                hsb += dot4(hB4[q], hB4[q]);
                float4 wa = scale4(fabs4(hA4), pAh);
                hrm[q] = wa;
                // halo rows live in lanes 0-15 / 16-31 of wave 0: lane+-1 with
                // gj clamps never crosses the 16-lane row group
                float4 lft = shfl4(wa, lane - 1);
                if (gj > 0) hrm[q] = max4(hrm[q], lft);
                float4 rgt = shfl4(wa, lane + 1);
                if (gj < 15) hrm[q] = max4(hrm[q], rgt);
            }
        }
        // owned-cell register terms + shfl row-max (rows = 16 contiguous lanes)
#pragma unroll
        for (int q = 0; q < CF4; q++) {
            float4 d = sub4(cB[q], cA[q]);
            zdiff += dot4(d, d);
            sa += dot4(cA[q], cA[q]);
            sb += dot4(cB[q], cB[q]);
            dots[4] += dot4(cA[q], cB[q]);
            float4 wa = scale4(fabs4(cA[q]), pAc);
            rm[q] = wa;
            float4 lft = shfl4(wa, lane - 1);
            if (gj > 0) rm[q] = max4(rm[q], lft);
            float4 rgt = shfl4(wa, lane + 1);
            if (gj < 15) rm[q] = max4(rm[q], rgt);
            shS[(lr * 16 + gj) * ST + q] = cB[q];      // stage owned B
        }
        if (isHalo) {
#pragma unroll
            for (int q = 0; q < CF4; q++) shS[(hs * 16 + gj) * ST + q] = hB4[q];
        }
        __syncthreads();

        // neighbor dots: A(own, regs) . B(neighbor, LDS) — local rows always valid
#pragma unroll
        for (int k = 0; k < 9; k++) {
            if (k == 4) continue;
            int base = nbl[k] * ST;
#pragma unroll
            for (int q = 0; q < CF4; q++) dots[k] += dot4(cA[q], shS[base + q]);
        }
        __syncthreads();   // all B reads done; overwrite with row-max

#pragma unroll
        for (int q = 0; q < CF4; q++) shS[(lr * 16 + gj) * ST + q] = rm[q];
        if (isHalo) {
#pragma unroll
            for (int q = 0; q < CF4; q++) shS[(hs * 16 + gj) * ST + q] = hrm[q];
        }
        __syncthreads();

        // pool: clamped col-max of row-max (global row bounds), dot/norm accum
        const bool up = (grow > 0), dn = (grow < 15);
#pragma unroll
        for (int q = 0; q < CF4; q++) {
            float4 sm = rm[q];
            if (up) sm = max4(sm, shS[((lr - 1) * 16 + gj) * ST + q]);
            if (dn) sm = max4(sm, shS[((lr + 1) * 16 + gj) * ST + q]);
            poolDot += dot4(sm, fabs4(cB[q]));
            poolN += dot4(sm, sm);
        }
        __syncthreads();   // before next chunk re-stages shS
    }

    // ---- epilogues ----
    nBloc[lr * 16 + gj] = sqrtf(sb);
    if (isHalo) nBloc[hs * 16 + gj] = sqrtf(hsb);
    __syncthreads();

    // objects (wrapped neighbors: local rows cover the wrap via halo)
    float prior_n = fmaxf(sqrtf(sa), 1e-8f);
    float sum_sim = 0.f, max_sim = -1e30f;
    bool has = false;
#pragma unroll
    for (int k = 0; k < 9; k++) {
        float nn = fmaxf(nBloc[nbl[k]], 1e-8f);
        float s = dots[k] / (prior_n * nn);
        if (pBloc[nbl[k]] > 0.5f) {
            sum_sim += s;
            max_sim = fmaxf(max_sim, s);
            has = true;
        }
    }
    float obj = ((pAc > 0.5f) && has) ? (sum_sim - 5.0f * max_sim) : 0.f;

    // pool
    float na_pool = fmaxf(sqrtf(poolN), 1e-6f);
    float nb_pool = fmaxf(pBc * sqrtf(sb), 1e-6f);
    float poolc = -(pBc * poolDot) / (na_pool * nb_pool) * 0.5f * (pAc + pBc);

    // flow (clamped 3x3 max of zp over image t; t=6 block also handles image 7)
    float mx = pAc;
#pragma unroll
    for (int k = 0; k < 9; k++)
        if (k != 4 && ((inbM >> k) & 1u)) mx = fmaxf(mx, pAloc[nbl[k]]);
    float fsq = 0.f;
    if (f > 0.5f) { float d = mx - f; fsq = d * d; }
    float szp = pAc, sflow = f;
    if (t == 6) {
        float mxB = pBc;
#pragma unroll
        for (int k = 0; k < 9; k++)
            if (k != 4 && ((inbM >> k) & 1u)) mxB = fmaxf(mxB, pBloc[nbl[k]]);
        if (f7 > 0.5f) { float d = mxB - f7; fsq += d * d; }
        szp += pBc;
        sflow += f7;
    }

    // pres triple (t, t+1, t+2) for t <= 5
    float pres = 0.f;
    if (t <= 5) {
        float s02 = pC - pAc;
        float sim = 1.f - s02 * s02;
        float d2 = pC - pBc, d0 = pAc - pBc;
        pres = sim * (d2 * d2 + d0 * d0);
    }

    // ---- block reduce 7 scalars (2 waves) -> private partial slot ----
    float r[7] = {zdiff, pres, poolc, obj, fsq, szp, sflow};
    int w = tid >> 6;
#pragma unroll
    for (int j = 0; j < 7; j++) {
        float rv = wred(r[j]);
        if (lane == 0) bred[j][w] = rv;
    }
    __syncthreads();
    if (tid < 7)
        part[blk * 8 + tid] = bred[tid][0] + bred[tid][1];
}

__global__ __launch_bounds__(256) void final_kernel(const float* __restrict__ part,
                                                    const int* __restrict__ gs,
                                                    float* __restrict__ out) {
    const int tid = threadIdx.x;
    __shared__ float bred[7][4];
    float c[7] = {0.f, 0.f, 0.f, 0.f, 0.f, 0.f, 0.f};
    for (int p = tid; p < NBLK; p += 256) {
        const float* r = part + p * 8;
#pragma unroll
        for (int j = 0; j < 7; j++) c[j] += r[j];
    }
    int w = tid >> 6, lane = tid & 63;
#pragma unroll
    for (int j = 0; j < 7; j++) {
        float rv = wred(c[j]);
        if (lane == 0) bred[j][w] = rv;
    }
    __syncthreads();
    if (tid == 0) {
        float s[7];
#pragma unroll
        for (int j = 0; j < 7; j++) s[j] = bred[j][0] + bred[j][1] + bred[j][2] + bred[j][3];
        float step = (float)gs[0];
        float scale_obj = fminf(1.f, step / 200000.f);
        float scale_flow = fmaxf(0.f, 1.f - step / 100000.f);
        float flow_loss = s[4] + 100.f * fmaxf(0.f, s[5] - s[6]);
        out[0] = s[0]                       // z_what_loss * ADJ_W
               + s[1]                       // z_pres_loss * PRES_W
               + s[2]                       // pool (already negated) * POOL_W
               + s[3] * scale_obj * 10.0f   // objects * OBJ_W
               + flow_loss * scale_flow;    // FLOW_W = 1
    }
}

extern "C" void kernel_launch(void* const* d_in, const int* in_sizes, int n_in,
                              void* d_out, int out_size, void* d_ws, size_t ws_size,
                              hipStream_t stream) {
    const float* zw = (const float*)d_in[0];
    const float* zp = (const float*)d_in[1];
    const float* fl = (const float*)d_in[2];
    const int* gs = (const int*)d_in[3];
    float* ws = (float*)d_ws;

    pair_kernel<<<NBLK, 128, 0, stream>>>(zw, zp, fl, ws);
    final_kernel<<<1, 256, 0, stream>>>(ws, gs, (float*)d_out);
}